// Round 10
// baseline (300.232 us; speedup 1.0000x reference)
//
#include <hip/hip_runtime.h>

#define HID 128
#define CLS 10
#define RCAP 64  // padded CSR row capacity; deg ~ Poisson(12), P(>=64) ~ 1e-34

typedef short short8 __attribute__((ext_vector_type(8)));
typedef float f32x4 __attribute__((ext_vector_type(4)));

// Sliced feature layout: T[s][node][32] bf16, s in 0..3; node==n is the zero row.
// Slice = 3.2MB -> fits one XCD's 4MiB L2 when a launch touches only one slice.

// float -> bf16 round-to-nearest-even
__device__ __forceinline__ unsigned short f2bf(float f) {
  union { float f; unsigned u; } v; v.f = f;
  unsigned u = v.u;
  return (unsigned short)((u + 0x7FFFu + ((u >> 16) & 1u)) >> 16);
}
__device__ __forceinline__ float bf_lo(unsigned p) { return __uint_as_float(p << 16); }
__device__ __forceinline__ float bf_hi(unsigned p) { return __uint_as_float(p & 0xFFFF0000u); }

// ---------------- setup: zero degi + pooled + slice zero-rows ----------------

__global__ __launch_bounds__(256) void zero_init(int* __restrict__ degi, int n,
                                                 float* __restrict__ pooled, int gh,
                                                 unsigned short* __restrict__ Ta,
                                                 unsigned short* __restrict__ Tb) {
  int i = blockIdx.x * 256 + threadIdx.x;
  if (i < n) degi[i] = 0;
  if (i < gh) pooled[i] = 0.f;
  if (blockIdx.x == 0 && threadIdx.x < 32) {  // zero rows: 2 buffers x 4 slices x 64B
    int buf = threadIdx.x >> 4;
    int s = (threadIdx.x >> 2) & 3;
    int c = threadIdx.x & 3;
    unsigned short* T = buf ? Tb : Ta;
    uint4 z; z.x = z.y = z.z = z.w = 0u;
    *(uint4*)&T[((size_t)s * (n + 1) + n) * 32 + c * 8] = z;
  }
}

// degree histogram + padded-CSR fill; tail blocks build bf16-transposed Wt (R9-proven)
__global__ __launch_bounds__(256) void degree_fill_wt(const int* __restrict__ src,
                                                      const int* __restrict__ dst,
                                                      int* __restrict__ degi,
                                                      int* __restrict__ col_src, int E, int nbE,
                                                      const float* __restrict__ W1,
                                                      const float* __restrict__ W2,
                                                      const float* __restrict__ W3,
                                                      unsigned short* __restrict__ Wt) {
  int b = blockIdx.x;
  if (b < nbE) {
    int e = b * 256 + threadIdx.x;
    if (e >= E) return;
    int d = dst[e];
    int slot = atomicAdd(&degi[d], 1);
    if (slot < RCAP) col_src[(size_t)d * RCAP + slot] = src[e];
    return;
  }
  int wb = b - nbE;
  int mat = wb >> 4;
  int part = wb & 15;
  const float* W = (mat == 0) ? W1 : (mat == 1) ? W2 : W3;
  unsigned short* o = Wt + (size_t)mat * HID * HID;
  int base = part * (HID * HID / 16);
  for (int r = 0; r < HID * HID / 16; r += 256) {
    int idx = base + r + threadIdx.x;
    int k = idx >> 7, nn = idx & 127;
    o[nn * HID + k] = f2bf(W[idx]);   // Wt[n][k] = W[k][n]
  }
}

// ---------------- MFMA bf16 GEMM (layer 1): sliced output ----------------

#define WTP 136  // 128 + 8 pad

__global__ __launch_bounds__(256) void gemm_mfma(const float* __restrict__ Aptr,
                                                 const unsigned short* __restrict__ Wt,
                                                 const int* __restrict__ degi,
                                                 unsigned short* __restrict__ Tb,  // sliced
                                                 int* __restrict__ pad_col,
                                                 int nrows) {
  __shared__ unsigned short sW[HID][WTP];
  int tid = threadIdx.x;
  int wave = tid >> 6, lane = tid & 63;
  int m_lo = lane & 15, quad = lane >> 4;
  int row0 = blockIdx.x * 128;
  int rbase = row0 + wave * 32;

  uint4 araw[2][4];
#pragma unroll
  for (int tr = 0; tr < 2; ++tr) {
    int grow = rbase + tr * 16 + m_lo;
    int gr = (grow < nrows) ? grow : (nrows - 1);
    const float* Arow = Aptr + (size_t)gr * HID;
#pragma unroll
    for (int kb = 0; kb < 4; ++kb) {
      float4 f0 = *(const float4*)&Arow[kb * 32 + quad * 8];
      float4 f1 = *(const float4*)&Arow[kb * 32 + quad * 8 + 4];
      uint4 u;
      u.x = (unsigned)f2bf(f0.x) | ((unsigned)f2bf(f0.y) << 16);
      u.y = (unsigned)f2bf(f0.z) | ((unsigned)f2bf(f0.w) << 16);
      u.z = (unsigned)f2bf(f1.x) | ((unsigned)f2bf(f1.y) << 16);
      u.w = (unsigned)f2bf(f1.z) | ((unsigned)f2bf(f1.w) << 16);
      araw[tr][kb] = u;
    }
  }

  const uint4* Wt4 = (const uint4*)Wt;
#pragma unroll
  for (int i = 0; i < 8; ++i) {
    int idx = i * 256 + tid;
    *(uint4*)&sW[idx >> 4][(idx & 15) * 8] = Wt4[idx];
  }
  __syncthreads();

  f32x4 acc[2][8];
#pragma unroll
  for (int tr = 0; tr < 2; ++tr)
#pragma unroll
    for (int tc = 0; tc < 8; ++tc) acc[tr][tc] = (f32x4)(0.f);

#pragma unroll
  for (int kb = 0; kb < 4; ++kb) {
    short8 b[8];
#pragma unroll
    for (int tc = 0; tc < 8; ++tc) {
      union { uint4 u; short8 s; } cv;
      cv.u = *(const uint4*)&sW[tc * 16 + m_lo][kb * 32 + quad * 8];
      b[tc] = cv.s;
    }
#pragma unroll
    for (int tr = 0; tr < 2; ++tr) {
      union { uint4 u; short8 s; } av;
      av.u = araw[tr][kb];
#pragma unroll
      for (int tc = 0; tc < 8; ++tc)
        acc[tr][tc] = __builtin_amdgcn_mfma_f32_16x16x32_bf16(av.s, b[tc], acc[tr][tc], 0, 0, 0);
    }
  }

#pragma unroll
  for (int tr = 0; tr < 2; ++tr) {
#pragma unroll
    for (int r = 0; r < 4; ++r) {
      int grow = rbase + tr * 16 + quad * 4 + r;
      if (grow < nrows) {
        int dgv = degi[grow];
        float s = rsqrtf((float)dgv + 1.0f);
        // feature col = tc*16+m_lo -> slice tc>>1, offset (tc&1)*16+m_lo
#pragma unroll
        for (int tc = 0; tc < 8; ++tc)
          Tb[((size_t)(tc >> 1) * (nrows + 1) + grow) * 32 + (tc & 1) * 16 + m_lo] =
              f2bf(s * acc[tr][tc][r]);
        if (m_lo == 0) {
          int d = dgv < RCAP ? dgv : RCAP;
          int dp = (d + 3) & ~3;
          for (int sl = d; sl < dp; ++sl)
            pad_col[(size_t)grow * RCAP + sl] = nrows;  // dummy -> zero row
        }
      }
    }
  }
}

// ---------------- slice gather core ----------------
// 16-lane group per node, quad q (4 lanes) covers neighbors j === q (mod 4);
// lane sub (l4&3) owns feats [sub*8, sub*8+8) of the slice. Paired loop keeps
// 2 gathers in flight per lane; quad-reduce via shfl_xor(4)+shfl_xor(8).

__device__ __forceinline__ void slice_gather(const unsigned short* __restrict__ Tslice,
                                             const int* __restrict__ row,
                                             int node, int dp, int q, int sub, float a[8]) {
  if (q == 0) {  // self-loop counted once
    uint4 sv = *(const uint4*)&Tslice[(size_t)node * 32 + sub * 8];
    a[0] = bf_lo(sv.x); a[1] = bf_hi(sv.x); a[2] = bf_lo(sv.y); a[3] = bf_hi(sv.y);
    a[4] = bf_lo(sv.z); a[5] = bf_hi(sv.z); a[6] = bf_lo(sv.w); a[7] = bf_hi(sv.w);
  } else {
#pragma unroll
    for (int k = 0; k < 8; ++k) a[k] = 0.f;
  }
  int j = q;
  for (; j + 4 < dp; j += 8) {
    int i0 = row[j], i1 = row[j + 4];
    uint4 v0 = *(const uint4*)&Tslice[(size_t)i0 * 32 + sub * 8];
    uint4 v1 = *(const uint4*)&Tslice[(size_t)i1 * 32 + sub * 8];
    a[0] += bf_lo(v0.x); a[1] += bf_hi(v0.x); a[2] += bf_lo(v0.y); a[3] += bf_hi(v0.y);
    a[4] += bf_lo(v0.z); a[5] += bf_hi(v0.z); a[6] += bf_lo(v0.w); a[7] += bf_hi(v0.w);
    a[0] += bf_lo(v1.x); a[1] += bf_hi(v1.x); a[2] += bf_lo(v1.y); a[3] += bf_hi(v1.y);
    a[4] += bf_lo(v1.z); a[5] += bf_hi(v1.z); a[6] += bf_lo(v1.w); a[7] += bf_hi(v1.w);
  }
  if (j < dp) {
    int i0 = row[j];
    uint4 v0 = *(const uint4*)&Tslice[(size_t)i0 * 32 + sub * 8];
    a[0] += bf_lo(v0.x); a[1] += bf_hi(v0.x); a[2] += bf_lo(v0.y); a[3] += bf_hi(v0.y);
    a[4] += bf_lo(v0.z); a[5] += bf_hi(v0.z); a[6] += bf_lo(v0.w); a[7] += bf_hi(v0.w);
  }
#pragma unroll
  for (int k = 0; k < 8; ++k) {
    a[k] += __shfl_xor(a[k], 4, 64);
    a[k] += __shfl_xor(a[k], 8, 64);
  }
}

// slices 0..2 of layers 1,2: gather slice s -> H slice s in global (32 nodes/block)
__global__ __launch_bounds__(256) void agg_slice(const unsigned short* __restrict__ Tin,
                                                 const int* __restrict__ degi,
                                                 const int* __restrict__ col_src,
                                                 const float* __restrict__ bias,
                                                 unsigned short* __restrict__ Hout,
                                                 int n, int s) {
  int tid = threadIdx.x;
  int g = tid >> 4, l4 = tid & 15;
  int q = l4 >> 2, sub = l4 & 3;
  const unsigned short* Tslice = Tin + (size_t)s * (n + 1) * 32;
  float4 b0 = *(const float4*)&bias[s * 32 + sub * 8];
  float4 b1 = *(const float4*)&bias[s * 32 + sub * 8 + 4];
  for (int c = 0; c < 2; ++c) {
    int node = blockIdx.x * 32 + g * 2 + c;
    if (node >= n) return;  // uniform within the 16-lane group
    int deg = degi[node];
    int dc = deg < RCAP ? deg : RCAP;
    int dp = (dc + 3) & ~3;
    const int* row = &col_src[(size_t)node * RCAP];
    float a[8];
    slice_gather(Tslice, row, node, dp, q, sub, a);
    float di = rsqrtf((float)deg + 1.0f);
    a[0] = fmaxf(di * a[0] + b0.x, 0.f); a[1] = fmaxf(di * a[1] + b0.y, 0.f);
    a[2] = fmaxf(di * a[2] + b0.z, 0.f); a[3] = fmaxf(di * a[3] + b0.w, 0.f);
    a[4] = fmaxf(di * a[4] + b1.x, 0.f); a[5] = fmaxf(di * a[5] + b1.y, 0.f);
    a[6] = fmaxf(di * a[6] + b1.z, 0.f); a[7] = fmaxf(di * a[7] + b1.w, 0.f);
    if (q == 0) {
      uint4 o;
      o.x = (unsigned)f2bf(a[0]) | ((unsigned)f2bf(a[1]) << 16);
      o.y = (unsigned)f2bf(a[2]) | ((unsigned)f2bf(a[3]) << 16);
      o.z = (unsigned)f2bf(a[4]) | ((unsigned)f2bf(a[5]) << 16);
      o.w = (unsigned)f2bf(a[6]) | ((unsigned)f2bf(a[7]) << 16);
      *(uint4*)&Hout[((size_t)s * (n + 1) + node) * 32 + sub * 8] = o;
    }
  }
}

// slice 3 + GEMM: gather slice 3 into LDS, stage H slices 0..2 from global,
// then 16x128 MFMA vs W, writing T_{l+1} sliced (keeps R6's fusion).
__global__ __launch_bounds__(256, 4) void agg_slice_gemm(const unsigned short* __restrict__ Tin,
                                                         const int* __restrict__ degi,
                                                         const int* __restrict__ col_src,
                                                         const float* __restrict__ bias,
                                                         const unsigned short* __restrict__ Hs,
                                                         const unsigned short* __restrict__ Wt,
                                                         unsigned short* __restrict__ Tout,
                                                         int n) {
  __shared__ unsigned short sW[HID][WTP];  // 34.8 KB
  __shared__ unsigned short sH[16][WTP];   // 4.3 KB
  int tid = threadIdx.x;

  const uint4* Wt4 = (const uint4*)Wt;
#pragma unroll
  for (int i = 0; i < 8; ++i) {
    int idx = i * 256 + tid;
    *(uint4*)&sW[idx >> 4][(idx & 15) * 8] = Wt4[idx];
  }

  // stage H slices 0..2 for the block's 16 nodes (192 x 16B, coalesced-ish)
  if (tid < 192) {
    int node_l = tid / 12;
    int r = tid % 12;
    int s2 = r >> 2, c = r & 3;
    int gnode = blockIdx.x * 16 + node_l;
    if (gnode >= n) gnode = n - 1;  // clamped rows feed guarded stores only
    uint4 v = *(const uint4*)&Hs[((size_t)s2 * (n + 1) + gnode) * 32 + c * 8];
    *(uint4*)&sH[node_l][s2 * 32 + c * 8] = v;
  }

  // gather slice 3 (one node per 16-lane group)
  int g = tid >> 4, l4 = tid & 15;
  int q = l4 >> 2, sub = l4 & 3;
  int node = blockIdx.x * 16 + g;
  int nodec = node < n ? node : (n - 1);
  const unsigned short* Tslice = Tin + (size_t)3 * (n + 1) * 32;
  {
    int deg = degi[nodec];
    int dc = deg < RCAP ? deg : RCAP;
    int dp = (dc + 3) & ~3;
    const int* row = &col_src[(size_t)nodec * RCAP];
    float a[8];
    slice_gather(Tslice, row, nodec, dp, q, sub, a);
    float di = rsqrtf((float)deg + 1.0f);
    float4 b0 = *(const float4*)&bias[96 + sub * 8];
    float4 b1 = *(const float4*)&bias[96 + sub * 8 + 4];
    a[0] = fmaxf(di * a[0] + b0.x, 0.f); a[1] = fmaxf(di * a[1] + b0.y, 0.f);
    a[2] = fmaxf(di * a[2] + b0.z, 0.f); a[3] = fmaxf(di * a[3] + b0.w, 0.f);
    a[4] = fmaxf(di * a[4] + b1.x, 0.f); a[5] = fmaxf(di * a[5] + b1.y, 0.f);
    a[6] = fmaxf(di * a[6] + b1.z, 0.f); a[7] = fmaxf(di * a[7] + b1.w, 0.f);
    if (q == 0) {
      uint4 o;
      o.x = (unsigned)f2bf(a[0]) | ((unsigned)f2bf(a[1]) << 16);
      o.y = (unsigned)f2bf(a[2]) | ((unsigned)f2bf(a[3]) << 16);
      o.z = (unsigned)f2bf(a[4]) | ((unsigned)f2bf(a[5]) << 16);
      o.w = (unsigned)f2bf(a[6]) | ((unsigned)f2bf(a[7]) << 16);
      *(uint4*)&sH[g][96 + sub * 8] = o;
    }
  }
  __syncthreads();

  // GEMM: T_out[16 rows] = dinv * (sH @ W). 4 waves x 2 col-tiles each.
  int wid = tid >> 6, lane = tid & 63;
  int m_lo = lane & 15, quad = lane >> 4;
  f32x4 acc[2];
  acc[0] = (f32x4)(0.f); acc[1] = (f32x4)(0.f);
#pragma unroll
  for (int kb = 0; kb < 4; ++kb) {
    union { uint4 u; short8 s; } av;
    av.u = *(const uint4*)&sH[m_lo][kb * 32 + quad * 8];
#pragma unroll
    for (int t = 0; t < 2; ++t) {
      int tc = wid * 2 + t;
      union { uint4 u; short8 s; } bv;
      bv.u = *(const uint4*)&sW[tc * 16 + m_lo][kb * 32 + quad * 8];
      acc[t] = __builtin_amdgcn_mfma_f32_16x16x32_bf16(av.s, bv.s, acc[t], 0, 0, 0);
    }
  }
#pragma unroll
  for (int r = 0; r < 4; ++r) {
    int grow = blockIdx.x * 16 + quad * 4 + r;
    if (grow < n) {
      float s = rsqrtf((float)degi[grow] + 1.0f);
#pragma unroll
      for (int t = 0; t < 2; ++t) {
        int tc = wid * 2 + t;
        Tout[((size_t)(tc >> 1) * (n + 1) + grow) * 32 + (tc & 1) * 16 + m_lo] =
            f2bf(s * acc[t][r]);
      }
    }
  }
}

// layer 3: per-slice aggregate + mean-pool partials (atomics into pooled)
__global__ __launch_bounds__(256) void pool_slice(const unsigned short* __restrict__ Tin,
                                                  const int* __restrict__ degi,
                                                  const int* __restrict__ col_src,
                                                  const float* __restrict__ bias,
                                                  const int* __restrict__ batch,
                                                  float* __restrict__ pooled, int n, int s) {
  __shared__ float sP[16][36];
  int tid = threadIdx.x;
  int g = tid >> 4, l4 = tid & 15;
  int q = l4 >> 2, sub = l4 & 3;
  int base = blockIdx.x * 16;
  int node = base + g;
  const unsigned short* Tslice = Tin + (size_t)s * (n + 1) * 32;
  if (node < n) {
    int deg = degi[node];
    int dc = deg < RCAP ? deg : RCAP;
    int dp = (dc + 3) & ~3;
    const int* row = &col_src[(size_t)node * RCAP];
    float a[8];
    slice_gather(Tslice, row, node, dp, q, sub, a);
    float di = rsqrtf((float)deg + 1.0f);
    float4 b0 = *(const float4*)&bias[s * 32 + sub * 8];
    float4 b1 = *(const float4*)&bias[s * 32 + sub * 8 + 4];
    a[0] = fmaxf(di * a[0] + b0.x, 0.f); a[1] = fmaxf(di * a[1] + b0.y, 0.f);
    a[2] = fmaxf(di * a[2] + b0.z, 0.f); a[3] = fmaxf(di * a[3] + b0.w, 0.f);
    a[4] = fmaxf(di * a[4] + b1.x, 0.f); a[5] = fmaxf(di * a[5] + b1.y, 0.f);
    a[6] = fmaxf(di * a[6] + b1.z, 0.f); a[7] = fmaxf(di * a[7] + b1.w, 0.f);
    if (q == 0) {
      *(float4*)&sP[g][sub * 8] = make_float4(a[0], a[1], a[2], a[3]);
      *(float4*)&sP[g][sub * 8 + 4] = make_float4(a[4], a[5], a[6], a[7]);
    }
  }
  __syncthreads();

  if (tid < 32) {
    int f = tid;
    int gq = -1;
    float acc = 0.f;
    for (int i = 0; i < 16; ++i) {
      int nd = base + i;
      if (nd >= n) break;
      int bi = batch[nd];
      if (bi != gq) {
        if (gq >= 0) atomicAdd(&pooled[gq * HID + s * 32 + f], acc);
        acc = 0.f;
        gq = bi;
      }
      acc += sP[i][f];
    }
    if (gq >= 0) atomicAdd(&pooled[gq * HID + s * 32 + f], acc);
  }
}

__global__ __launch_bounds__(128) void classify_k(const float* __restrict__ pooled,
                                                  const int* __restrict__ batch,
                                                  const float* __restrict__ Wl,
                                                  const float* __restrict__ bl,
                                                  float* __restrict__ out, int n) {
  int g = blockIdx.x;
  int t = threadIdx.x;
  int lo = 0, hi = n;
  while (lo < hi) { int mid = (lo + hi) >> 1; if (batch[mid] < g) lo = mid + 1; else hi = mid; }
  int s = lo;
  hi = n;
  while (lo < hi) { int mid = (lo + hi) >> 1; if (batch[mid] < g + 1) lo = mid + 1; else hi = mid; }
  float c = fmaxf((float)(lo - s), 1.0f);
  __shared__ float p[HID];
  p[t] = pooled[g * HID + t] / c;
  __syncthreads();
  if (t < CLS) {
    float o = bl[t];
    for (int j = 0; j < HID; ++j) o += p[j] * Wl[j * CLS + t];
    out[g * CLS + t] = o;
  }
}

// ---------------- launch ----------------

extern "C" void kernel_launch(void* const* d_in, const int* in_sizes, int n_in,
                              void* d_out, int out_size, void* d_ws, size_t ws_size,
                              hipStream_t stream) {
  const float* x  = (const float*)d_in[0];
  const float* W1 = (const float*)d_in[1];
  const float* b1 = (const float*)d_in[2];
  const float* W2 = (const float*)d_in[3];
  const float* b2 = (const float*)d_in[4];
  const float* W3 = (const float*)d_in[5];
  const float* b3 = (const float*)d_in[6];
  const float* Wl = (const float*)d_in[7];
  const float* bl = (const float*)d_in[8];
  const int* edge_index = (const int*)d_in[9];
  const int* batch = (const int*)d_in[10];

  const int N = in_sizes[10];
  const int E = in_sizes[9] / 2;
  const int G = out_size / CLS;
  const int* src = edge_index;
  const int* dst = edge_index + E;

  uintptr_t p = (uintptr_t)d_ws;
  auto take = [&](size_t bytes) -> void* {
    void* r = (void*)p;
    p += (bytes + 255) & ~(size_t)255;
    return r;
  };
  int*      degi      = (int*)take((size_t)N * 4);
  int*      col_src   = (int*)take((size_t)N * RCAP * 4);  // padded CSR, 12.8 MB
  unsigned short* WtA = (unsigned short*)take((size_t)3 * HID * HID * 2);
  unsigned short* bufTa = (unsigned short*)take((size_t)(N + 1) * HID * 2);  // sliced
  unsigned short* bufTb = (unsigned short*)take((size_t)(N + 1) * HID * 2);  // sliced
  unsigned short* bufH  = (unsigned short*)take((size_t)(N + 1) * HID * 2);  // sliced (0..2 used)
  float*    pooled    = (float*)take((size_t)G * HID * 4);

  int nbN = (N + 255) / 256;
  int nbE = (E + 255) / 256;

  zero_init<<<nbN, 256, 0, stream>>>(degi, N, pooled, G * HID, bufTa, bufTb);
  degree_fill_wt<<<nbE + 48, 256, 0, stream>>>(src, dst, degi, col_src, E, nbE,
                                               W1, W2, W3, WtA);

  int gemmBlocks = (N + 127) / 128;
  int sliceBlocks = (N + 31) / 32;   // agg_slice: 32 nodes/block
  int aggBlocks = (N + 15) / 16;     // agg_slice_gemm / pool_slice: 16 nodes/block

  // layer 1 GEMM: x @ W1 -> T1 (A, sliced), pads CSR rows
  gemm_mfma<<<gemmBlocks, 256, 0, stream>>>(x, WtA, degi, bufTa, col_src, N);

  // layer 1 aggregate (sliced) fused with layer 2 GEMM: T1(A) -> T2(B)
  for (int s = 0; s < 3; ++s)
    agg_slice<<<sliceBlocks, 256, 0, stream>>>(bufTa, degi, col_src, b1, bufH, N, s);
  agg_slice_gemm<<<aggBlocks, 256, 0, stream>>>(bufTa, degi, col_src, b1, bufH,
                                                WtA + (size_t)HID * HID, bufTb, N);

  // layer 2 aggregate (sliced) fused with layer 3 GEMM: T2(B) -> T3(A)
  for (int s = 0; s < 3; ++s)
    agg_slice<<<sliceBlocks, 256, 0, stream>>>(bufTb, degi, col_src, b2, bufH, N, s);
  agg_slice_gemm<<<aggBlocks, 256, 0, stream>>>(bufTb, degi, col_src, b2, bufH,
                                                WtA + (size_t)2 * HID * HID, bufTa, N);

  // layer 3 aggregate + pool, per slice
  for (int s = 0; s < 4; ++s)
    pool_slice<<<aggBlocks, 256, 0, stream>>>(bufTa, degi, col_src, b3, batch, pooled, N, s);

  classify_k<<<G, 128, 0, stream>>>(pooled, batch, Wl, bl, (float*)d_out, N);
}

// Round 11
// 226.016 us; speedup vs baseline: 1.3284x; 1.3284x over previous
//
#include <hip/hip_runtime.h>

#define HID 128
#define CLS 10
#define RCAP 64  // padded CSR row capacity; deg ~ Poisson(12), P(>=64) ~ 1e-34

typedef short short8 __attribute__((ext_vector_type(8)));
typedef float f32x4 __attribute__((ext_vector_type(4)));

// float -> bf16 round-to-nearest-even
__device__ __forceinline__ unsigned short f2bf(float f) {
  union { float f; unsigned u; } v; v.f = f;
  unsigned u = v.u;
  return (unsigned short)((u + 0x7FFFu + ((u >> 16) & 1u)) >> 16);
}
__device__ __forceinline__ float bf_lo(unsigned p) { return __uint_as_float(p << 16); }
__device__ __forceinline__ float bf_hi(unsigned p) { return __uint_as_float(p & 0xFFFF0000u); }

// ---------------- setup: zero degi + pooled + T zero-rows ----------------

__global__ __launch_bounds__(256) void zero_init(int* __restrict__ degi, int n,
                                                 float* __restrict__ pooled, int gh,
                                                 unsigned short* __restrict__ TzA,
                                                 unsigned short* __restrict__ TzB) {
  int i = blockIdx.x * 256 + threadIdx.x;
  if (i < n) degi[i] = 0;
  if (i < gh) pooled[i] = 0.f;
  if (blockIdx.x == 0 && threadIdx.x < 16) {  // zero dummy rows (index N) of both T buffers
    uint4 z; z.x = z.y = z.z = z.w = 0u;
    *(uint4*)&TzA[threadIdx.x * 8] = z;
    *(uint4*)&TzB[threadIdx.x * 8] = z;
  }
}

// degree histogram + padded-CSR fill; tail blocks (independent work) build the
// bf16-transposed weights Wt[n][k] for all three layers in the same launch
// (Wt build hides under the edge scatter instead of the tiny zero kernel).
__global__ __launch_bounds__(256) void degree_fill_wt(const int* __restrict__ src,
                                                      const int* __restrict__ dst,
                                                      int* __restrict__ degi,
                                                      int* __restrict__ col_src, int E, int nbE,
                                                      const float* __restrict__ W1,
                                                      const float* __restrict__ W2,
                                                      const float* __restrict__ W3,
                                                      unsigned short* __restrict__ Wt) {
  int b = blockIdx.x;
  if (b < nbE) {
    int e = b * 256 + threadIdx.x;
    if (e >= E) return;
    int d = dst[e];
    int slot = atomicAdd(&degi[d], 1);
    if (slot < RCAP) col_src[(size_t)d * RCAP + slot] = src[e];
    return;
  }
  int wb = b - nbE;                  // 0..47
  int mat = wb >> 4;                 // 0..2
  int part = wb & 15;                // 0..15
  const float* W = (mat == 0) ? W1 : (mat == 1) ? W2 : W3;
  unsigned short* o = Wt + (size_t)mat * HID * HID;
  int base = part * (HID * HID / 16);
  for (int r = 0; r < HID * HID / 16; r += 256) {
    int idx = base + r + threadIdx.x;
    int k = idx >> 7, nn = idx & 127;
    o[nn * HID + k] = f2bf(W[idx]);   // Wt[n][k] = W[k][n]
  }
}

// ---------------- MFMA bf16 GEMM (layer 1): Tb[r,:] = bf16( dinv[r] * (x[r,:] @ W) ) ----
// Block = 4 waves x 32 rows = 128 rows. W staged in LDS; A fragments direct
// global->VGPR (fp32 x converted in-register). Also pads each CSR row to a
// multiple of 4 with dummy index `nrows` (the zero row) - persistent for all layers.

#define WTP 136  // 128 + 8 pad

__global__ __launch_bounds__(256) void gemm_mfma(const float* __restrict__ Aptr,
                                                 const unsigned short* __restrict__ Wt,  // bf16 [n][k]
                                                 const int* __restrict__ degi,
                                                 unsigned short* __restrict__ Tb,  // bf16 [n][128]
                                                 int* __restrict__ pad_col,
                                                 int nrows) {
  __shared__ unsigned short sW[HID][WTP];
  int tid = threadIdx.x;
  int wave = tid >> 6, lane = tid & 63;
  int m_lo = lane & 15, quad = lane >> 4;
  int row0 = blockIdx.x * 128;
  int rbase = row0 + wave * 32;

  uint4 araw[2][4];
#pragma unroll
  for (int tr = 0; tr < 2; ++tr) {
    int grow = rbase + tr * 16 + m_lo;
    int gr = (grow < nrows) ? grow : (nrows - 1);  // clamp: stores guarded later
    const float* Arow = Aptr + (size_t)gr * HID;
#pragma unroll
    for (int kb = 0; kb < 4; ++kb) {
      float4 f0 = *(const float4*)&Arow[kb * 32 + quad * 8];
      float4 f1 = *(const float4*)&Arow[kb * 32 + quad * 8 + 4];
      uint4 u;
      u.x = (unsigned)f2bf(f0.x) | ((unsigned)f2bf(f0.y) << 16);
      u.y = (unsigned)f2bf(f0.z) | ((unsigned)f2bf(f0.w) << 16);
      u.z = (unsigned)f2bf(f1.x) | ((unsigned)f2bf(f1.y) << 16);
      u.w = (unsigned)f2bf(f1.z) | ((unsigned)f2bf(f1.w) << 16);
      araw[tr][kb] = u;
    }
  }

  const uint4* Wt4 = (const uint4*)Wt;
#pragma unroll
  for (int i = 0; i < 8; ++i) {
    int idx = i * 256 + tid;
    *(uint4*)&sW[idx >> 4][(idx & 15) * 8] = Wt4[idx];
  }
  __syncthreads();

  f32x4 acc[2][8];
#pragma unroll
  for (int tr = 0; tr < 2; ++tr)
#pragma unroll
    for (int tc = 0; tc < 8; ++tc) acc[tr][tc] = (f32x4)(0.f);

#pragma unroll
  for (int kb = 0; kb < 4; ++kb) {
    short8 b[8];
#pragma unroll
    for (int tc = 0; tc < 8; ++tc) {
      union { uint4 u; short8 s; } cv;
      cv.u = *(const uint4*)&sW[tc * 16 + m_lo][kb * 32 + quad * 8];
      b[tc] = cv.s;
    }
#pragma unroll
    for (int tr = 0; tr < 2; ++tr) {
      union { uint4 u; short8 s; } av;
      av.u = araw[tr][kb];
#pragma unroll
      for (int tc = 0; tc < 8; ++tc)
        acc[tr][tc] = __builtin_amdgcn_mfma_f32_16x16x32_bf16(av.s, b[tc], acc[tr][tc], 0, 0, 0);
    }
  }

#pragma unroll
  for (int tr = 0; tr < 2; ++tr) {
#pragma unroll
    for (int r = 0; r < 4; ++r) {
      int grow = rbase + tr * 16 + quad * 4 + r;
      if (grow < nrows) {
        int dgv = degi[grow];
        float s = rsqrtf((float)dgv + 1.0f);  // dinv inline
        unsigned short* orow = &Tb[(size_t)grow * HID];
#pragma unroll
        for (int tc = 0; tc < 8; ++tc)
          orow[tc * 16 + m_lo] = f2bf(s * acc[tr][tc][r]);
        if (m_lo == 0) {
          int d = dgv < RCAP ? dgv : RCAP;
          int dp = (d + 3) & ~3;
          for (int sl = d; sl < dp; ++sl)
            pad_col[(size_t)grow * RCAP + sl] = nrows;  // dummy -> zero row
        }
      }
    }
  }
}

// ---------------- aggregate core (R2/R6-proven): 16-lane group per node ----------------
// CSR rows padded to x4 with the zero-row index: pure 8/4-chunks, 8 gathers in
// flight per group (32/wave), no scalar tail. Plain cached index loads: col_src
// is reused across all three layers (nt loads regressed, R8).

__device__ __forceinline__ void agg_node(const unsigned* __restrict__ Tb2,
                                         const int* __restrict__ degi,
                                         const int* __restrict__ col_src,
                                         const float* __restrict__ bias,
                                         int node, int l4, float a[8]) {
  uint4 sv = *(const uint4*)&Tb2[(size_t)node * 64 + l4 * 4];
  a[0] = bf_lo(sv.x); a[1] = bf_hi(sv.x); a[2] = bf_lo(sv.y); a[3] = bf_hi(sv.y);
  a[4] = bf_lo(sv.z); a[5] = bf_hi(sv.z); a[6] = bf_lo(sv.w); a[7] = bf_hi(sv.w);
  int deg = degi[node];
  int dc = deg < RCAP ? deg : RCAP;
  int dp = (dc + 3) & ~3;       // padded length (pad slots point at zero row)
  const int* row = &col_src[(size_t)node * RCAP];
  int j = 0;
  for (; j + 8 <= dp; j += 8) {
    int idx[8];
#pragma unroll
    for (int u = 0; u < 8; ++u) idx[u] = row[j + u];
    uint4 v[8];
#pragma unroll
    for (int u = 0; u < 8; ++u) v[u] = *(const uint4*)&Tb2[(size_t)idx[u] * 64 + l4 * 4];
#pragma unroll
    for (int u = 0; u < 8; ++u) {
      a[0] += bf_lo(v[u].x); a[1] += bf_hi(v[u].x);
      a[2] += bf_lo(v[u].y); a[3] += bf_hi(v[u].y);
      a[4] += bf_lo(v[u].z); a[5] += bf_hi(v[u].z);
      a[6] += bf_lo(v[u].w); a[7] += bf_hi(v[u].w);
    }
  }
  if (j < dp) {  // exactly one 4-chunk (dp - j == 4)
    int idx[4];
#pragma unroll
    for (int u = 0; u < 4; ++u) idx[u] = row[j + u];
    uint4 v[4];
#pragma unroll
    for (int u = 0; u < 4; ++u) v[u] = *(const uint4*)&Tb2[(size_t)idx[u] * 64 + l4 * 4];
#pragma unroll
    for (int u = 0; u < 4; ++u) {
      a[0] += bf_lo(v[u].x); a[1] += bf_hi(v[u].x);
      a[2] += bf_lo(v[u].y); a[3] += bf_hi(v[u].y);
      a[4] += bf_lo(v[u].z); a[5] += bf_hi(v[u].z);
      a[6] += bf_lo(v[u].w); a[7] += bf_hi(v[u].w);
    }
  }
  float di = rsqrtf((float)deg + 1.0f);
  float4 bs0 = *(const float4*)&bias[l4 * 8];
  float4 bs1 = *(const float4*)&bias[l4 * 8 + 4];
  a[0] = fmaxf(di * a[0] + bs0.x, 0.f);
  a[1] = fmaxf(di * a[1] + bs0.y, 0.f);
  a[2] = fmaxf(di * a[2] + bs0.z, 0.f);
  a[3] = fmaxf(di * a[3] + bs0.w, 0.f);
  a[4] = fmaxf(di * a[4] + bs1.x, 0.f);
  a[5] = fmaxf(di * a[5] + bs1.y, 0.f);
  a[6] = fmaxf(di * a[6] + bs1.z, 0.f);
  a[7] = fmaxf(di * a[7] + bs1.w, 0.f);
}

// ---------------- fused aggregate + next-layer GEMM (R6-proven) ----------------

__global__ __launch_bounds__(256, 4) void fused_agg_gemm(const unsigned* __restrict__ Tb_in,
                                                         const int* __restrict__ degi,
                                                         const int* __restrict__ col_src,
                                                         const float* __restrict__ bias,
                                                         const unsigned short* __restrict__ Wt,
                                                         unsigned short* __restrict__ Tb_out,
                                                         int n) {
  __shared__ unsigned short sW[HID][WTP];  // 34.8 KB
  __shared__ unsigned short sH[16][WTP];   // 4.3 KB
  int tid = threadIdx.x;

  // stage W (issued before gathers; completes long before the barrier)
  const uint4* Wt4 = (const uint4*)Wt;
#pragma unroll
  for (int i = 0; i < 8; ++i) {
    int idx = i * 256 + tid;
    *(uint4*)&sW[idx >> 4][(idx & 15) * 8] = Wt4[idx];
  }

  // phase 1: aggregate 16 nodes (one 16-lane group per node)
  int nl = tid >> 4, l4 = tid & 15;
  int node = blockIdx.x * 16 + nl;
  int nodec = node < n ? node : (n - 1);
  float a[8];
  agg_node(Tb_in, degi, col_src, bias, nodec, l4, a);
  uint4 o;
  o.x = (unsigned)f2bf(a[0]) | ((unsigned)f2bf(a[1]) << 16);
  o.y = (unsigned)f2bf(a[2]) | ((unsigned)f2bf(a[3]) << 16);
  o.z = (unsigned)f2bf(a[4]) | ((unsigned)f2bf(a[5]) << 16);
  o.w = (unsigned)f2bf(a[6]) | ((unsigned)f2bf(a[7]) << 16);
  *(uint4*)&sH[nl][l4 * 8] = o;
  __syncthreads();

  // phase 2: T_out[16 rows] = dinv * (sH @ W). 4 waves x 2 col-tiles each.
  int wid = tid >> 6, lane = tid & 63;
  int m_lo = lane & 15, quad = lane >> 4;
  f32x4 acc[2];
  acc[0] = (f32x4)(0.f); acc[1] = (f32x4)(0.f);
#pragma unroll
  for (int kb = 0; kb < 4; ++kb) {
    union { uint4 u; short8 s; } av;
    av.u = *(const uint4*)&sH[m_lo][kb * 32 + quad * 8];
#pragma unroll
    for (int t = 0; t < 2; ++t) {
      int tc = wid * 2 + t;
      union { uint4 u; short8 s; } bv;
      bv.u = *(const uint4*)&sW[tc * 16 + m_lo][kb * 32 + quad * 8];
      acc[t] = __builtin_amdgcn_mfma_f32_16x16x32_bf16(av.s, bv.s, acc[t], 0, 0, 0);
    }
  }
#pragma unroll
  for (int r = 0; r < 4; ++r) {
    int grow = blockIdx.x * 16 + quad * 4 + r;
    if (grow < n) {
      float s = rsqrtf((float)degi[grow] + 1.0f);
      unsigned short* orow = &Tb_out[(size_t)grow * HID];
#pragma unroll
      for (int t = 0; t < 2; ++t) {
        int tc = wid * 2 + t;
        orow[tc * 16 + m_lo] = f2bf(s * acc[t][r]);
      }
    }
  }
}

// layer 3: no T output; pool directly (block = 16 consecutive nodes, run-detected
// atomics into pooled) — R6-proven
#define SPP 132  // 128 + 4 pad floats

__global__ __launch_bounds__(256) void aggregate_pool(const unsigned* __restrict__ Tb2,
                                                      const int* __restrict__ degi,
                                                      const int* __restrict__ col_src,
                                                      const float* __restrict__ bias,
                                                      const int* __restrict__ batch,
                                                      float* __restrict__ pooled, int n) {
  __shared__ float sP[16][SPP];  // 8.25 KB
  int tid = threadIdx.x;
  int wave = tid >> 6, lane = tid & 63;
  int sub = lane >> 4;
  int l4 = lane & 15;
  int base = blockIdx.x * 16;
  int nl = wave * 4 + sub;       // 0..15
  int node = base + nl;
  bool active = (node < n);

  float a[8] = {0.f, 0.f, 0.f, 0.f, 0.f, 0.f, 0.f, 0.f};
  if (active) agg_node(Tb2, degi, col_src, bias, node, l4, a);
  *(float4*)&sP[nl][l4 * 8] = make_float4(a[0], a[1], a[2], a[3]);
  *(float4*)&sP[nl][l4 * 8 + 4] = make_float4(a[4], a[5], a[6], a[7]);
  __syncthreads();

  if (tid < HID) {
    int g = -1;
    float acc = 0.f;
    for (int i = 0; i < 16; ++i) {
      int nd = base + i;
      if (nd >= n) break;
      int bi = batch[nd];
      if (bi != g) {
        if (g >= 0) atomicAdd(&pooled[g * HID + tid], acc);
        acc = 0.f;
        g = bi;
      }
      acc += sP[i][tid];
    }
    if (g >= 0) atomicAdd(&pooled[g * HID + tid], acc);
  }
}

__global__ __launch_bounds__(128) void classify_k(const float* __restrict__ pooled,
                                                  const int* __restrict__ batch,
                                                  const float* __restrict__ Wl,
                                                  const float* __restrict__ bl,
                                                  float* __restrict__ out, int n) {
  int g = blockIdx.x;
  int t = threadIdx.x;
  int lo = 0, hi = n;
  while (lo < hi) { int mid = (lo + hi) >> 1; if (batch[mid] < g) lo = mid + 1; else hi = mid; }
  int s = lo;
  hi = n;
  while (lo < hi) { int mid = (lo + hi) >> 1; if (batch[mid] < g + 1) lo = mid + 1; else hi = mid; }
  float c = fmaxf((float)(lo - s), 1.0f);
  __shared__ float p[HID];
  p[t] = pooled[g * HID + t] / c;
  __syncthreads();
  if (t < CLS) {
    float o = bl[t];
    for (int j = 0; j < HID; ++j) o += p[j] * Wl[j * CLS + t];
    out[g * CLS + t] = o;
  }
}

// ---------------- launch ----------------

extern "C" void kernel_launch(void* const* d_in, const int* in_sizes, int n_in,
                              void* d_out, int out_size, void* d_ws, size_t ws_size,
                              hipStream_t stream) {
  const float* x  = (const float*)d_in[0];
  const float* W1 = (const float*)d_in[1];
  const float* b1 = (const float*)d_in[2];
  const float* W2 = (const float*)d_in[3];
  const float* b2 = (const float*)d_in[4];
  const float* W3 = (const float*)d_in[5];
  const float* b3 = (const float*)d_in[6];
  const float* Wl = (const float*)d_in[7];
  const float* bl = (const float*)d_in[8];
  const int* edge_index = (const int*)d_in[9];
  const int* batch = (const int*)d_in[10];

  const int N = in_sizes[10];
  const int E = in_sizes[9] / 2;
  const int G = out_size / CLS;
  const int* src = edge_index;
  const int* dst = edge_index + E;

  uintptr_t p = (uintptr_t)d_ws;
  auto take = [&](size_t bytes) -> void* {
    void* r = (void*)p;
    p += (bytes + 255) & ~(size_t)255;
    return r;
  };
  int*      degi      = (int*)take((size_t)N * 4);
  int*      col_src   = (int*)take((size_t)N * RCAP * 4);  // padded CSR, 12.8 MB
  unsigned short* WtA = (unsigned short*)take((size_t)3 * HID * HID * 2);
  unsigned short* bufTa = (unsigned short*)take((size_t)(N + 1) * HID * 2);  // +1 zero row
  unsigned short* bufTb = (unsigned short*)take((size_t)(N + 1) * HID * 2);  // +1 zero row
  float*    pooled    = (float*)take((size_t)G * HID * 4);

  int nbN = (N + 255) / 256;
  int nbE = (E + 255) / 256;

  zero_init<<<nbN, 256, 0, stream>>>(degi, N, pooled, G * HID,
                                     bufTa + (size_t)N * HID, bufTb + (size_t)N * HID);
  degree_fill_wt<<<nbE + 48, 256, 0, stream>>>(src, dst, degi, col_src, E, nbE,
                                               W1, W2, W3, WtA);

  int gemmBlocks = (N + 127) / 128;
  int aggBlocks = (N + 15) / 16;   // 16 nodes per 256-thr block

  // layer 1 GEMM: x @ W1 -> T1 (A), also pads CSR rows
  gemm_mfma<<<gemmBlocks, 256, 0, stream>>>(x, WtA, degi, bufTa, col_src, N);
  // layer 1 aggregate fused with layer 2 GEMM: T1 (A) -> T2 (B)
  fused_agg_gemm<<<aggBlocks, 256, 0, stream>>>((unsigned*)bufTa, degi, col_src, b1,
                                                WtA + (size_t)HID * HID, bufTb, N);
  // layer 2 aggregate fused with layer 3 GEMM: T2 (B) -> T3 (A)
  fused_agg_gemm<<<aggBlocks, 256, 0, stream>>>((unsigned*)bufTb, degi, col_src, b2,
                                                WtA + (size_t)2 * HID * HID, bufTa, N);
  // layer 3 aggregate + pool
  aggregate_pool<<<aggBlocks, 256, 0, stream>>>((unsigned*)bufTa, degi, col_src, b3,
                                                batch, pooled, N);
  classify_k<<<G, 128, 0, stream>>>(pooled, batch, Wl, bl, (float*)d_out, N);
}